// Round 18
// baseline (259.156 us; speedup 1.0000x reference)
//
#include <hip/hip_runtime.h>
#include <limits.h>

#define N_GRID 128
#define N_GRID3 (N_GRID * N_GRID * N_GRID)   // 2097152 cells/nodes

constexpr int   N_PART   = 500000;
constexpr float DT       = 0.0002f;
constexpr float DX       = 1.0f / 128.0f;
constexpr float INV_DX   = 128.0f;
constexpr float P_MASS   = 5.9604644775390625e-05f;   // (DX*0.5)^3 * 1000
constexpr float AFF_COEF = -7.8125e-07f;              // -DT * P_VOL * 4 * INV_DX^2
constexpr float GRAVITY  = 9.8f;
constexpr int   BOUND    = 3;
constexpr float C_SCALE  = 65536.0f;                  // 4 * INV_DX^2
constexpr int   ZQ       = 2;  // measured sweet spot (R11/R13/R16/R17 post-mortems)

// ---------------- pass 1: cell histogram + per-block bbox partials ----------------
__global__ __launch_bounds__(256) void k_count(const float* __restrict__ x,
                                               int* __restrict__ cnt,
                                               int* __restrict__ blkMin,
                                               int* __restrict__ blkMax) {
  __shared__ int lmin[12], lmax[12];  // 4 waves x 3 axes
  int n = blockIdx.x * 256 + threadIdx.x;
  int bx = INT_MAX, by = INT_MAX, bz = INT_MAX;
  int mx = -1, my = -1, mz = -1;
  if (n < N_PART) {
    bx = min(max((int)floorf(x[n * 3 + 0] * INV_DX - 0.5f), 0), N_GRID - 1);
    by = min(max((int)floorf(x[n * 3 + 1] * INV_DX - 0.5f), 0), N_GRID - 1);
    bz = min(max((int)floorf(x[n * 3 + 2] * INV_DX - 0.5f), 0), N_GRID - 1);
    int c = (bx << 14) | (by << 7) | bz;
    atomicAdd(&cnt[c], 1);  // 2M spread addresses: uncontended
    mx = bx; my = by; mz = bz;
  }
#pragma unroll
  for (int d = 32; d > 0; d >>= 1) {
    bx = min(bx, __shfl_xor(bx, d));
    by = min(by, __shfl_xor(by, d));
    bz = min(bz, __shfl_xor(bz, d));
    mx = max(mx, __shfl_xor(mx, d));
    my = max(my, __shfl_xor(my, d));
    mz = max(mz, __shfl_xor(mz, d));
  }
  int lane = threadIdx.x & 63, wid = threadIdx.x >> 6;
  if (lane == 0) {
    lmin[wid * 3 + 0] = bx; lmin[wid * 3 + 1] = by; lmin[wid * 3 + 2] = bz;
    lmax[wid * 3 + 0] = mx; lmax[wid * 3 + 1] = my; lmax[wid * 3 + 2] = mz;
  }
  __syncthreads();
  if (threadIdx.x == 0) {
    int b = blockIdx.x;
#pragma unroll
    for (int a = 0; a < 3; ++a) {
      blkMin[b * 3 + a] = min(min(lmin[a], lmin[3 + a]), min(lmin[6 + a], lmin[9 + a]));
      blkMax[b * 3 + a] = max(max(lmax[a], lmax[3 + a]), max(lmax[6 + a], lmax[9 + a]));
    }
  }
}

// ---------------- pass 2a: block sums (2048 blocks x 1024 bins) ----------------
__global__ __launch_bounds__(256) void k_scan1(const int* __restrict__ cnt,
                                               int* __restrict__ blkSum) {
  __shared__ int ws[4];
  int tid = threadIdx.x, lane = tid & 63, wid = tid >> 6;
  int4 v = ((const int4*)cnt)[blockIdx.x * 256 + tid];
  int s = v.x + v.y + v.z + v.w;
  for (int d = 32; d > 0; d >>= 1) s += __shfl_down(s, d);
  if (lane == 0) ws[wid] = s;
  __syncthreads();
  if (tid == 0) blkSum[blockIdx.x] = ws[0] + ws[1] + ws[2] + ws[3];
}

// ------- pass 2b: scan 2048 block sums + reduce bbox partials (1 workgroup) -------
__global__ __launch_bounds__(256) void k_scan2(const int* __restrict__ blkSum,
                                               int* __restrict__ blkOff,
                                               int* __restrict__ start,
                                               const int* __restrict__ blkMin,
                                               const int* __restrict__ blkMax,
                                               int nblkP,
                                               int* __restrict__ bbox) {
  __shared__ int wsum[4];
  __shared__ int rmin[12], rmax[12];
  int tid = threadIdx.x, lane = tid & 63, wid = tid >> 6;

  int base = tid * 8;
  int s[8], tot = 0;
#pragma unroll
  for (int j = 0; j < 8; ++j) { s[j] = blkSum[base + j]; tot += s[j]; }
  int incl = tot;
  for (int d = 1; d < 64; d <<= 1) {
    int t = __shfl_up(incl, d);
    if (lane >= d) incl += t;
  }
  if (lane == 63) wsum[wid] = incl;
  __syncthreads();
  int woff = 0;
  for (int w = 0; w < wid; ++w) woff += wsum[w];
  int run = woff + incl - tot;
#pragma unroll
  for (int j = 0; j < 8; ++j) { blkOff[base + j] = run; run += s[j]; }
  if (tid == 255) start[N_GRID3] = run;  // == N_PART

  int bx = INT_MAX, by = INT_MAX, bz = INT_MAX;
  int mx = -1, my = -1, mz = -1;
  for (int j = tid; j < nblkP; j += 256) {
    bx = min(bx, blkMin[j * 3 + 0]);
    by = min(by, blkMin[j * 3 + 1]);
    bz = min(bz, blkMin[j * 3 + 2]);
    mx = max(mx, blkMax[j * 3 + 0]);
    my = max(my, blkMax[j * 3 + 1]);
    mz = max(mz, blkMax[j * 3 + 2]);
  }
#pragma unroll
  for (int d = 32; d > 0; d >>= 1) {
    bx = min(bx, __shfl_xor(bx, d));
    by = min(by, __shfl_xor(by, d));
    bz = min(bz, __shfl_xor(bz, d));
    mx = max(mx, __shfl_xor(mx, d));
    my = max(my, __shfl_xor(my, d));
    mz = max(mz, __shfl_xor(mz, d));
  }
  if (lane == 0) {
    rmin[wid * 3 + 0] = bx; rmin[wid * 3 + 1] = by; rmin[wid * 3 + 2] = bz;
    rmax[wid * 3 + 0] = mx; rmax[wid * 3 + 1] = my; rmax[wid * 3 + 2] = mz;
  }
  __syncthreads();
  if (tid == 0) {
#pragma unroll
    for (int a = 0; a < 3; ++a) {
      bbox[a]     = min(min(rmin[a], rmin[3 + a]), min(rmin[6 + a], rmin[9 + a]));
      bbox[3 + a] = max(max(rmax[a], rmax[3 + a]), max(rmax[6 + a], rmax[9 + a]));
    }
  }
}

// ------- pass 2c: in-block exclusive scan + offset; cursor written over cnt -------
__global__ __launch_bounds__(256) void k_scan3(int* __restrict__ cnt,
                                               const int* __restrict__ blkOff,
                                               int* __restrict__ start) {
  __shared__ int wsum[4];
  int tid = threadIdx.x, lane = tid & 63, wid = tid >> 6;
  int b = blockIdx.x;
  int4 v = ((const int4*)cnt)[b * 256 + tid];
  int s = v.x + v.y + v.z + v.w;
  int incl = s;
  for (int d = 1; d < 64; d <<= 1) {
    int t = __shfl_up(incl, d);
    if (lane >= d) incl += t;
  }
  if (lane == 63) wsum[wid] = incl;
  __syncthreads();
  int woff = blkOff[b];
  for (int w = 0; w < wid; ++w) woff += wsum[w];
  int run = woff + incl - s;
  int i0 = (b * 256 + tid) * 4;
  int r0 = run, r1 = r0 + v.x, r2 = r1 + v.y, r3 = r2 + v.z;
  start[i0 + 0] = r0; start[i0 + 1] = r1; start[i0 + 2] = r2; start[i0 + 3] = r3;
  cnt[i0 + 0] = r0; cnt[i0 + 1] = r1; cnt[i0 + 2] = r2; cnt[i0 + 3] = r3;  // cursor
}

// ---------------- pass 3: reorder into SPLIT payload (F does NOT cross) ----------------
// posO[pos] = (px,py,pz,ORIG) ; aux[3*pos..] = {(mvx,mvy,mvz,a0),(a1..a4),(a5..a8)}
__global__ __launch_bounds__(256) void k_reorder(
    const float* __restrict__ x, const float* __restrict__ v,
    const float* __restrict__ C, const float* __restrict__ S,
    int* __restrict__ cursor, float4* __restrict__ posO,
    float4* __restrict__ aux) {
  int n = blockIdx.x * 256 + threadIdx.x;
  if (n >= N_PART) return;

  float px = x[n * 3 + 0], py = x[n * 3 + 1], pz = x[n * 3 + 2];
  int bx = min(max((int)floorf(px * INV_DX - 0.5f), 0), N_GRID - 1);
  int by = min(max((int)floorf(py * INV_DX - 0.5f), 0), N_GRID - 1);
  int bz = min(max((int)floorf(pz * INV_DX - 0.5f), 0), N_GRID - 1);
  int c = (bx << 14) | (by << 7) | bz;
  int pos = atomicAdd(&cursor[c], 1);

  float mvx = P_MASS * v[n * 3 + 0];
  float mvy = P_MASS * v[n * 3 + 1];
  float mvz = P_MASS * v[n * 3 + 2];
  float aff[9];
#pragma unroll
  for (int k = 0; k < 9; ++k)
    aff[k] = AFF_COEF * S[n * 9 + k] + P_MASS * C[n * 9 + k];

  posO[pos] = make_float4(px, py, pz, __int_as_float(n));
  float4* dst = aux + (size_t)pos * 3;
  dst[0] = make_float4(mvx, mvy, mvz, aff[0]);
  dst[1] = make_float4(aff[1], aff[2], aff[3], aff[4]);
  dst[2] = make_float4(aff[5], aff[6], aff[7], aff[8]);
}

// quadratic B-spline weight for static offset o (folds after unroll)
__device__ __forceinline__ float wq(int o, float f) {
  if (o == 0) return 0.5f * (1.5f - f) * (1.5f - f);
  if (o == 1) return 0.75f - (f - 1.0f) * (f - 1.0f);
  return 0.5f * (f - 0.5f) * (f - 0.5f);
}

// ---------------- P2G gather: dense bbox launch + bijective XCD swizzle ----------------
__global__ __launch_bounds__(256) void mpm_p2g(
    const int* __restrict__ start, const float4* __restrict__ posO,
    const float4* __restrict__ aux, const int* __restrict__ bbox,
    float* __restrict__ grid /* [N_GRID3][4] final velocities */) {
  int bx0 = bbox[0], by0 = bbox[1], bz0c = bbox[2];
  int nxd = bbox[3] - bx0 + 3;
  int nyd = bbox[4] - by0 + 3;
  int nzd = bbox[5] - bz0c + 3;
  int dimzq = (nzd + ZQ - 1) / ZQ;
  int vol = nxd * nyd * dimzq;
  int nact = (vol + 255) >> 8;

  int bid = blockIdx.x;
  if (bid >= nact) return;
  int q = nact >> 3, r = nact & 7;
  int xcd = bid & 7, sub = bid >> 3;
  int wgid = (xcd < r ? xcd * (q + 1) : r * (q + 1) + (xcd - r) * q) + sub;

  int t = wgid * 256 + (int)threadIdx.x;
  if (t >= vol) return;
  int izq = t % dimzq;
  int rr = t / dimzq;
  int iy = rr % nyd;
  int ix = rr / nyd;
  int nx = bx0 + ix, ny = by0 + iy, nz0 = bz0c + izq * ZQ;
  if (nx > N_GRID - 1 || ny > N_GRID - 1) return;
  int zb0 = nz0 - 2;
  bool zint = (zb0 >= 0) && (zb0 + ZQ + 2 <= N_GRID);  // interior z-window

  float accx[ZQ], accy[ZQ], accz[ZQ], accm[ZQ];
#pragma unroll
  for (int k = 0; k < ZQ; ++k) { accx[k] = 0.f; accy[k] = 0.f; accz[k] = 0.f; accm[k] = 0.f; }
  int gotmask = 0;

#pragma unroll
  for (int dy = -2; dy <= 0; ++dy) {
    int cy = ny + dy;
    if (cy < 0) continue;
#pragma unroll
    for (int dx = -2; dx <= 0; ++dx) {
      int cx = nx + dx;
      if (cx < 0) continue;
      const int ox = -dx, oy = -dy;  // static after unroll
      int rowb = (cx << 14) | (cy << 7);

      int S[ZQ + 3];
      if (zint) {
#pragma unroll
        for (int j = 0; j < ZQ + 3; ++j) S[j] = start[rowb + zb0 + j];
      } else {
#pragma unroll
        for (int j = 0; j < ZQ + 3; ++j)
          S[j] = start[rowb + min(max(zb0 + j, 0), N_GRID)];
      }
#pragma unroll
      for (int k = 0; k < ZQ; ++k)
        gotmask |= (S[k + 3] > S[k]) ? (1 << k) : 0;

      for (int i = S[0]; i < S[ZQ + 2]; ++i) {
        float4 q0 = posO[i];
        const float4* ap = aux + (size_t)i * 3;
        float4 A0 = ap[0], A1 = ap[1], A2 = ap[2];

        float fx = q0.x * INV_DX - (float)cx;   // base_x == cx by construction
        float fy = q0.y * INV_DX - (float)cy;
        float gz = q0.z * INV_DX;
        float bzf = floorf(gz - 0.5f);
        float fz = gz - bzf;
        int oz0 = nz0 - (int)bzf;

        float wxy = wq(ox, fx) * wq(oy, fy);
        float dpx = ((float)ox - fx) * DX;
        float dpy = ((float)oy - fy) * DX;
        float wz0 = 0.5f * (1.5f - fz) * (1.5f - fz);
        float wz1 = 0.75f - (fz - 1.0f) * (fz - 1.0f);
        float wz2 = 0.5f * (fz - 0.5f) * (fz - 0.5f);

        // dpz-independent partial sums; dpz coeffs: a2=A1.y, a5=A2.x, a8=A2.w
        float sx = A0.x + A0.w * dpx + A1.x * dpy;
        float sy = A0.y + A1.z * dpx + A1.w * dpy;
        float sz = A0.z + A2.y * dpx + A2.z * dpy;
        float wm = wxy * P_MASS;

#pragma unroll
        for (int k = 0; k < ZQ; ++k) {
          int oz = oz0 + k;
          if (oz < 0 || oz > 2) continue;
          float wzz = (oz == 0) ? wz0 : ((oz == 1) ? wz1 : wz2);
          float w = wxy * wzz;
          float dpz = ((float)oz - fz) * DX;
          accx[k] += w * (sx + A1.y * dpz);
          accy[k] += w * (sy + A2.x * dpz);
          accz[k] += w * (sz + A2.w * dpz);
          accm[k] += wzz * wm;
        }
      }
    }
  }

  if (!gotmask) return;

  float4* g4 = (float4*)grid;
#pragma unroll
  for (int k = 0; k < ZQ; ++k) {
    int nz = nz0 + k;
    if (!((gotmask >> k) & 1) || nz > N_GRID - 1) continue;
    float m = accm[k];
    float ovx = 0.0f, ovy = 0.0f, ovz = 0.0f;
    if (m > 0.0f) {
      float inv = 1.0f / fmaxf(m, 1e-10f);
      ovx = accx[k] * inv;
      ovy = accy[k] * inv;
      ovz = accz[k] * inv;
      ovy -= DT * GRAVITY;
    }
    if (nx < BOUND && ovx < 0.0f) ovx = 0.0f;
    if (nx >= N_GRID - BOUND && ovx > 0.0f) ovx = 0.0f;
    if (ny < BOUND && ovy < 0.0f) ovy = 0.0f;
    if (ny >= N_GRID - BOUND && ovy > 0.0f) ovy = 0.0f;
    if (nz < BOUND && ovz < 0.0f) ovz = 0.0f;
    if (nz >= N_GRID - BOUND && ovz > 0.0f) ovz = 0.0f;
    g4[(nx << 14) | (ny << 7) | nz] = make_float4(ovx, ovy, ovz, m);
  }
}

// ---------------- G2P: sorted order; NT stores on scattered outputs ----------------
__global__ __launch_bounds__(256) void mpm_g2p(
    const float4* __restrict__ posO, const float* __restrict__ grid,
    float* __restrict__ out_x, float* __restrict__ out_v,
    float* __restrict__ out_C) {
  int i = blockIdx.x * blockDim.x + threadIdx.x;
  if (i >= N_PART) return;

  float4 q0 = posO[i];
  int n = __float_as_int(q0.w);  // original particle index

  float px = q0.x, py = q0.y, pz = q0.z;
  float gx = px * INV_DX, gy = py * INV_DX, gz = pz * INV_DX;
  int bx = (int)floorf(gx - 0.5f);
  int by = (int)floorf(gy - 0.5f);
  int bz = (int)floorf(gz - 0.5f);
  float fx = gx - (float)bx, fy = gy - (float)by, fz = gz - (float)bz;

  float wx[3], wy[3], wz[3];
  wx[0] = 0.5f * (1.5f - fx) * (1.5f - fx);
  wx[1] = 0.75f - (fx - 1.0f) * (fx - 1.0f);
  wx[2] = 0.5f * (fx - 0.5f) * (fx - 0.5f);
  wy[0] = 0.5f * (1.5f - fy) * (1.5f - fy);
  wy[1] = 0.75f - (fy - 1.0f) * (fy - 1.0f);
  wy[2] = 0.5f * (fy - 0.5f) * (fy - 0.5f);
  wz[0] = 0.5f * (1.5f - fz) * (1.5f - fz);
  wz[1] = 0.75f - (fz - 1.0f) * (fz - 1.0f);
  wz[2] = 0.5f * (fz - 0.5f) * (fz - 0.5f);

  float vnx = 0.0f, vny = 0.0f, vnz = 0.0f;
  float Cn[9];
#pragma unroll
  for (int k = 0; k < 9; ++k) Cn[k] = 0.0f;

  const float4* g4 = (const float4*)grid;
  bool interior = (bx >= 0) & (by >= 0) & (bz >= 0) &
                  (bx + 2 < N_GRID) & (by + 2 < N_GRID) & (bz + 2 < N_GRID);

  if (interior) {
    int flat0 = (bx << 14) | (by << 7) | bz;
#pragma unroll
    for (int a = 0; a < 3; ++a) {
#pragma unroll
      for (int bb = 0; bb < 3; ++bb) {
#pragma unroll
        for (int c = 0; c < 3; ++c) {
          float weight = wx[a] * wy[bb] * wz[c];
          float dpx = ((float)a - fx) * DX;
          float dpy = ((float)bb - fy) * DX;
          float dpz = ((float)c - fz) * DX;
          float4 g = g4[flat0 + (a << 14) + (bb << 7) + c];
          vnx += weight * g.x;
          vny += weight * g.y;
          vnz += weight * g.z;
          Cn[0] += weight * g.x * dpx;
          Cn[1] += weight * g.x * dpy;
          Cn[2] += weight * g.x * dpz;
          Cn[3] += weight * g.y * dpx;
          Cn[4] += weight * g.y * dpy;
          Cn[5] += weight * g.y * dpz;
          Cn[6] += weight * g.z * dpx;
          Cn[7] += weight * g.z * dpy;
          Cn[8] += weight * g.z * dpz;
        }
      }
    }
  } else {
#pragma unroll
    for (int a = 0; a < 3; ++a) {
#pragma unroll
      for (int bb = 0; bb < 3; ++bb) {
#pragma unroll
        for (int c = 0; c < 3; ++c) {
          float weight = wx[a] * wy[bb] * wz[c];
          float dpx = ((float)a - fx) * DX;
          float dpy = ((float)bb - fy) * DX;
          float dpz = ((float)c - fz) * DX;
          int nxg = min(max(bx + a, 0), N_GRID - 1);
          int nyg = min(max(by + bb, 0), N_GRID - 1);
          int nzg = min(max(bz + c, 0), N_GRID - 1);
          float4 g = g4[(nxg << 14) | (nyg << 7) | nzg];
          vnx += weight * g.x;
          vny += weight * g.y;
          vnz += weight * g.z;
          Cn[0] += weight * g.x * dpx;
          Cn[1] += weight * g.x * dpy;
          Cn[2] += weight * g.x * dpz;
          Cn[3] += weight * g.y * dpx;
          Cn[4] += weight * g.y * dpy;
          Cn[5] += weight * g.y * dpz;
          Cn[6] += weight * g.z * dpx;
          Cn[7] += weight * g.z * dpy;
          Cn[8] += weight * g.z * dpz;
        }
      }
    }
  }

#pragma unroll
  for (int k = 0; k < 9; ++k) Cn[k] *= C_SCALE;

  // scattered outputs: nontemporal stores (bypass cache allocation / RMW fills)
  __builtin_nontemporal_store(px + DT * vnx, &out_x[n * 3 + 0]);
  __builtin_nontemporal_store(py + DT * vny, &out_x[n * 3 + 1]);
  __builtin_nontemporal_store(pz + DT * vnz, &out_x[n * 3 + 2]);
  __builtin_nontemporal_store(vnx, &out_v[n * 3 + 0]);
  __builtin_nontemporal_store(vny, &out_v[n * 3 + 1]);
  __builtin_nontemporal_store(vnz, &out_v[n * 3 + 2]);
#pragma unroll
  for (int k = 0; k < 9; ++k)
    __builtin_nontemporal_store(Cn[k], &out_C[n * 9 + k]);
}

// ---------------- F epilogue: fully DENSE in n — F never crosses the sort ----------------
__global__ __launch_bounds__(256) void k_ffinal(
    const float* __restrict__ out_C, const float* __restrict__ F,
    float* __restrict__ out_F) {
  int n = blockIdx.x * blockDim.x + threadIdx.x;
  if (n >= N_PART) return;

  float A[9];
#pragma unroll
  for (int k = 0; k < 9; ++k) A[k] = DT * out_C[(size_t)n * 9 + k];
  A[0] += 1.0f; A[4] += 1.0f; A[8] += 1.0f;

  float Fl[9];
#pragma unroll
  for (int k = 0; k < 9; ++k) Fl[k] = F[(size_t)n * 9 + k];

#pragma unroll
  for (int r = 0; r < 3; ++r) {
#pragma unroll
    for (int k = 0; k < 3; ++k) {
      float s = A[r * 3 + 0] * Fl[0 * 3 + k] +
                A[r * 3 + 1] * Fl[1 * 3 + k] +
                A[r * 3 + 2] * Fl[2 * 3 + k];
      out_F[(size_t)n * 9 + r * 3 + k] = s;
    }
  }
}

extern "C" void kernel_launch(void* const* d_in, const int* in_sizes, int n_in,
                              void* d_out, int out_size, void* d_ws, size_t ws_size,
                              hipStream_t stream) {
  const float* x      = (const float*)d_in[0];
  const float* v      = (const float*)d_in[1];
  const float* C      = (const float*)d_in[2];
  const float* F      = (const float*)d_in[3];
  const float* stress = (const float*)d_in[4];

  float* out = (float*)d_out;
  char*  ws  = (char*)d_ws;

  const size_t GRID_BYTES  = (size_t)N_GRID3 * 4 * sizeof(float);   // 33.5 MB
  const size_t POSO_BYTES  = (size_t)N_PART * sizeof(float4);       // 8 MB
  const size_t AUX_BYTES   = (size_t)N_PART * 3 * sizeof(float4);   // 24 MB
  const size_t CNT_BYTES   = (size_t)N_GRID3 * sizeof(int);         // 8 MB
  const size_t START_BYTES = ((size_t)N_GRID3 + 1) * sizeof(int);   // 8 MB

  int pblocks = (N_PART + 255) / 256;  // 1954

  size_t off = 0;
  float*  grid   = (float*)(ws + off);  off += GRID_BYTES;
  float4* posO   = (float4*)(ws + off); off += POSO_BYTES;
  float4* aux    = (float4*)(ws + off); off += AUX_BYTES;
  int*    cnt    = (int*)(ws + off);    off += CNT_BYTES;
  int*    startp = (int*)(ws + off);    off += START_BYTES;
  int*    blkSum = (int*)(ws + off);    off += 2048 * sizeof(int);
  int*    blkOff = (int*)(ws + off);    off += 2048 * sizeof(int);
  int*    blkMin = (int*)(ws + off);    off += (size_t)pblocks * 3 * sizeof(int);
  int*    blkMax = (int*)(ws + off);    off += (size_t)pblocks * 3 * sizeof(int);
  int*    bbox   = (int*)(ws + off);    off += 16 * sizeof(int);

  hipMemsetAsync(cnt, 0, CNT_BYTES, stream);

  k_count<<<pblocks, 256, 0, stream>>>(x, cnt, blkMin, blkMax);
  k_scan1<<<2048, 256, 0, stream>>>(cnt, blkSum);
  k_scan2<<<1, 256, 0, stream>>>(blkSum, blkOff, startp, blkMin, blkMax, pblocks, bbox);
  k_scan3<<<2048, 256, 0, stream>>>(cnt, blkOff, startp);
  k_reorder<<<pblocks, 256, 0, stream>>>(x, v, C, stress, cnt, posO, aux);

  mpm_p2g<<<(N_GRID3 / ZQ + 255) / 256, 256, 0, stream>>>(startp, posO, aux, bbox, grid);

  float* out_x = out;
  float* out_v = out + (size_t)N_PART * 3;
  float* out_C = out + (size_t)N_PART * 6;
  float* out_F = out + (size_t)N_PART * 6 + (size_t)N_PART * 9;
  mpm_g2p<<<pblocks, 256, 0, stream>>>(posO, grid, out_x, out_v, out_C);
  k_ffinal<<<pblocks, 256, 0, stream>>>(out_C, F, out_F);
}

// Round 19
// 189.661 us; speedup vs baseline: 1.3664x; 1.3664x over previous
//
#include <hip/hip_runtime.h>
#include <limits.h>

#define N_GRID 128
#define N_GRID3 (N_GRID * N_GRID * N_GRID)   // 2097152 cells/nodes

constexpr int   N_PART   = 500000;
constexpr float DT       = 0.0002f;
constexpr float DX       = 1.0f / 128.0f;
constexpr float INV_DX   = 128.0f;
constexpr float P_MASS   = 5.9604644775390625e-05f;   // (DX*0.5)^3 * 1000
constexpr float AFF_COEF = -7.8125e-07f;              // -DT * P_VOL * 4 * INV_DX^2
constexpr float GRAVITY  = 9.8f;
constexpr int   BOUND    = 3;
constexpr float C_SCALE  = 65536.0f;                  // 4 * INV_DX^2
constexpr int   ZQ       = 2;  // measured sweet spot (R11/R13/R16/R17/R18 post-mortems)

// ---------------- pass 1: cell histogram + per-block bbox partials ----------------
__global__ __launch_bounds__(256) void k_count(const float* __restrict__ x,
                                               int* __restrict__ cnt,
                                               int* __restrict__ blkMin,
                                               int* __restrict__ blkMax) {
  __shared__ int lmin[12], lmax[12];  // 4 waves x 3 axes
  int n = blockIdx.x * 256 + threadIdx.x;
  int bx = INT_MAX, by = INT_MAX, bz = INT_MAX;
  int mx = -1, my = -1, mz = -1;
  if (n < N_PART) {
    bx = min(max((int)floorf(x[n * 3 + 0] * INV_DX - 0.5f), 0), N_GRID - 1);
    by = min(max((int)floorf(x[n * 3 + 1] * INV_DX - 0.5f), 0), N_GRID - 1);
    bz = min(max((int)floorf(x[n * 3 + 2] * INV_DX - 0.5f), 0), N_GRID - 1);
    int c = (bx << 14) | (by << 7) | bz;
    atomicAdd(&cnt[c], 1);  // 2M spread addresses: uncontended
    mx = bx; my = by; mz = bz;
  }
#pragma unroll
  for (int d = 32; d > 0; d >>= 1) {
    bx = min(bx, __shfl_xor(bx, d));
    by = min(by, __shfl_xor(by, d));
    bz = min(bz, __shfl_xor(bz, d));
    mx = max(mx, __shfl_xor(mx, d));
    my = max(my, __shfl_xor(my, d));
    mz = max(mz, __shfl_xor(mz, d));
  }
  int lane = threadIdx.x & 63, wid = threadIdx.x >> 6;
  if (lane == 0) {
    lmin[wid * 3 + 0] = bx; lmin[wid * 3 + 1] = by; lmin[wid * 3 + 2] = bz;
    lmax[wid * 3 + 0] = mx; lmax[wid * 3 + 1] = my; lmax[wid * 3 + 2] = mz;
  }
  __syncthreads();
  if (threadIdx.x == 0) {
    int b = blockIdx.x;
#pragma unroll
    for (int a = 0; a < 3; ++a) {
      blkMin[b * 3 + a] = min(min(lmin[a], lmin[3 + a]), min(lmin[6 + a], lmin[9 + a]));
      blkMax[b * 3 + a] = max(max(lmax[a], lmax[3 + a]), max(lmax[6 + a], lmax[9 + a]));
    }
  }
}

// ---------------- pass 2a: block sums (2048 blocks x 1024 bins) ----------------
__global__ __launch_bounds__(256) void k_scan1(const int* __restrict__ cnt,
                                               int* __restrict__ blkSum) {
  __shared__ int ws[4];
  int tid = threadIdx.x, lane = tid & 63, wid = tid >> 6;
  int4 v = ((const int4*)cnt)[blockIdx.x * 256 + tid];
  int s = v.x + v.y + v.z + v.w;
  for (int d = 32; d > 0; d >>= 1) s += __shfl_down(s, d);
  if (lane == 0) ws[wid] = s;
  __syncthreads();
  if (tid == 0) blkSum[blockIdx.x] = ws[0] + ws[1] + ws[2] + ws[3];
}

// ------- pass 2b: scan 2048 block sums + reduce bbox partials (1 workgroup) -------
__global__ __launch_bounds__(256) void k_scan2(const int* __restrict__ blkSum,
                                               int* __restrict__ blkOff,
                                               int* __restrict__ start,
                                               const int* __restrict__ blkMin,
                                               const int* __restrict__ blkMax,
                                               int nblkP,
                                               int* __restrict__ bbox) {
  __shared__ int wsum[4];
  __shared__ int rmin[12], rmax[12];
  int tid = threadIdx.x, lane = tid & 63, wid = tid >> 6;

  int base = tid * 8;
  int s[8], tot = 0;
#pragma unroll
  for (int j = 0; j < 8; ++j) { s[j] = blkSum[base + j]; tot += s[j]; }
  int incl = tot;
  for (int d = 1; d < 64; d <<= 1) {
    int t = __shfl_up(incl, d);
    if (lane >= d) incl += t;
  }
  if (lane == 63) wsum[wid] = incl;
  __syncthreads();
  int woff = 0;
  for (int w = 0; w < wid; ++w) woff += wsum[w];
  int run = woff + incl - tot;
#pragma unroll
  for (int j = 0; j < 8; ++j) { blkOff[base + j] = run; run += s[j]; }
  if (tid == 255) start[N_GRID3] = run;  // == N_PART

  int bx = INT_MAX, by = INT_MAX, bz = INT_MAX;
  int mx = -1, my = -1, mz = -1;
  for (int j = tid; j < nblkP; j += 256) {
    bx = min(bx, blkMin[j * 3 + 0]);
    by = min(by, blkMin[j * 3 + 1]);
    bz = min(bz, blkMin[j * 3 + 2]);
    mx = max(mx, blkMax[j * 3 + 0]);
    my = max(my, blkMax[j * 3 + 1]);
    mz = max(mz, blkMax[j * 3 + 2]);
  }
#pragma unroll
  for (int d = 32; d > 0; d >>= 1) {
    bx = min(bx, __shfl_xor(bx, d));
    by = min(by, __shfl_xor(by, d));
    bz = min(bz, __shfl_xor(bz, d));
    mx = max(mx, __shfl_xor(mx, d));
    my = max(my, __shfl_xor(my, d));
    mz = max(mz, __shfl_xor(mz, d));
  }
  if (lane == 0) {
    rmin[wid * 3 + 0] = bx; rmin[wid * 3 + 1] = by; rmin[wid * 3 + 2] = bz;
    rmax[wid * 3 + 0] = mx; rmax[wid * 3 + 1] = my; rmax[wid * 3 + 2] = mz;
  }
  __syncthreads();
  if (tid == 0) {
#pragma unroll
    for (int a = 0; a < 3; ++a) {
      bbox[a]     = min(min(rmin[a], rmin[3 + a]), min(rmin[6 + a], rmin[9 + a]));
      bbox[3 + a] = max(max(rmax[a], rmax[3 + a]), max(rmax[6 + a], rmax[9 + a]));
    }
  }
}

// ------- pass 2c: in-block exclusive scan + offset; cursor written over cnt -------
__global__ __launch_bounds__(256) void k_scan3(int* __restrict__ cnt,
                                               const int* __restrict__ blkOff,
                                               int* __restrict__ start) {
  __shared__ int wsum[4];
  int tid = threadIdx.x, lane = tid & 63, wid = tid >> 6;
  int b = blockIdx.x;
  int4 v = ((const int4*)cnt)[b * 256 + tid];
  int s = v.x + v.y + v.z + v.w;
  int incl = s;
  for (int d = 1; d < 64; d <<= 1) {
    int t = __shfl_up(incl, d);
    if (lane >= d) incl += t;
  }
  if (lane == 63) wsum[wid] = incl;
  __syncthreads();
  int woff = blkOff[b];
  for (int w = 0; w < wid; ++w) woff += wsum[w];
  int run = woff + incl - s;
  int i0 = (b * 256 + tid) * 4;
  int r0 = run, r1 = r0 + v.x, r2 = r1 + v.y, r3 = r2 + v.z;
  start[i0 + 0] = r0; start[i0 + 1] = r1; start[i0 + 2] = r2; start[i0 + 3] = r3;
  cnt[i0 + 0] = r0; cnt[i0 + 1] = r1; cnt[i0 + 2] = r2; cnt[i0 + 3] = r3;  // cursor
}

// ---------------- pass 3: reorder into SPLIT payload (F does NOT cross) ----------------
// posO[pos] = (px,py,pz,ORIG) ; aux[3*pos..] = {(mvx,mvy,mvz,a0),(a1..a4),(a5..a8)}
__global__ __launch_bounds__(256) void k_reorder(
    const float* __restrict__ x, const float* __restrict__ v,
    const float* __restrict__ C, const float* __restrict__ S,
    int* __restrict__ cursor, float4* __restrict__ posO,
    float4* __restrict__ aux) {
  int n = blockIdx.x * 256 + threadIdx.x;
  if (n >= N_PART) return;

  float px = x[n * 3 + 0], py = x[n * 3 + 1], pz = x[n * 3 + 2];
  int bx = min(max((int)floorf(px * INV_DX - 0.5f), 0), N_GRID - 1);
  int by = min(max((int)floorf(py * INV_DX - 0.5f), 0), N_GRID - 1);
  int bz = min(max((int)floorf(pz * INV_DX - 0.5f), 0), N_GRID - 1);
  int c = (bx << 14) | (by << 7) | bz;
  int pos = atomicAdd(&cursor[c], 1);

  float mvx = P_MASS * v[n * 3 + 0];
  float mvy = P_MASS * v[n * 3 + 1];
  float mvz = P_MASS * v[n * 3 + 2];
  float aff[9];
#pragma unroll
  for (int k = 0; k < 9; ++k)
    aff[k] = AFF_COEF * S[n * 9 + k] + P_MASS * C[n * 9 + k];

  posO[pos] = make_float4(px, py, pz, __int_as_float(n));
  float4* dst = aux + (size_t)pos * 3;
  dst[0] = make_float4(mvx, mvy, mvz, aff[0]);
  dst[1] = make_float4(aff[1], aff[2], aff[3], aff[4]);
  dst[2] = make_float4(aff[5], aff[6], aff[7], aff[8]);
}

// quadratic B-spline weight for static offset o (folds after unroll)
__device__ __forceinline__ float wq(int o, float f) {
  if (o == 0) return 0.5f * (1.5f - f) * (1.5f - f);
  if (o == 1) return 0.75f - (f - 1.0f) * (f - 1.0f);
  return 0.5f * (f - 0.5f) * (f - 0.5f);
}

// ---------------- P2G gather: dense bbox launch + bijective XCD swizzle ----------------
__global__ __launch_bounds__(256) void mpm_p2g(
    const int* __restrict__ start, const float4* __restrict__ posO,
    const float4* __restrict__ aux, const int* __restrict__ bbox,
    float* __restrict__ grid /* [N_GRID3][4] final velocities */) {
  int bx0 = bbox[0], by0 = bbox[1], bz0c = bbox[2];
  int nxd = bbox[3] - bx0 + 3;
  int nyd = bbox[4] - by0 + 3;
  int nzd = bbox[5] - bz0c + 3;
  int dimzq = (nzd + ZQ - 1) / ZQ;
  int vol = nxd * nyd * dimzq;
  int nact = (vol + 255) >> 8;

  int bid = blockIdx.x;
  if (bid >= nact) return;
  int q = nact >> 3, r = nact & 7;
  int xcd = bid & 7, sub = bid >> 3;
  int wgid = (xcd < r ? xcd * (q + 1) : r * (q + 1) + (xcd - r) * q) + sub;

  int t = wgid * 256 + (int)threadIdx.x;
  if (t >= vol) return;
  int izq = t % dimzq;
  int rr = t / dimzq;
  int iy = rr % nyd;
  int ix = rr / nyd;
  int nx = bx0 + ix, ny = by0 + iy, nz0 = bz0c + izq * ZQ;
  if (nx > N_GRID - 1 || ny > N_GRID - 1) return;
  int zb0 = nz0 - 2;
  bool zint = (zb0 >= 0) && (zb0 + ZQ + 2 <= N_GRID);  // interior z-window

  float accx[ZQ], accy[ZQ], accz[ZQ], accm[ZQ];
#pragma unroll
  for (int k = 0; k < ZQ; ++k) { accx[k] = 0.f; accy[k] = 0.f; accz[k] = 0.f; accm[k] = 0.f; }
  int gotmask = 0;

#pragma unroll
  for (int dy = -2; dy <= 0; ++dy) {
    int cy = ny + dy;
    if (cy < 0) continue;
#pragma unroll
    for (int dx = -2; dx <= 0; ++dx) {
      int cx = nx + dx;
      if (cx < 0) continue;
      const int ox = -dx, oy = -dy;  // static after unroll
      int rowb = (cx << 14) | (cy << 7);

      int S[ZQ + 3];
      if (zint) {
#pragma unroll
        for (int j = 0; j < ZQ + 3; ++j) S[j] = start[rowb + zb0 + j];
      } else {
#pragma unroll
        for (int j = 0; j < ZQ + 3; ++j)
          S[j] = start[rowb + min(max(zb0 + j, 0), N_GRID)];
      }
#pragma unroll
      for (int k = 0; k < ZQ; ++k)
        gotmask |= (S[k + 3] > S[k]) ? (1 << k) : 0;

      for (int i = S[0]; i < S[ZQ + 2]; ++i) {
        float4 q0 = posO[i];
        const float4* ap = aux + (size_t)i * 3;
        float4 A0 = ap[0], A1 = ap[1], A2 = ap[2];

        float fx = q0.x * INV_DX - (float)cx;   // base_x == cx by construction
        float fy = q0.y * INV_DX - (float)cy;
        float gz = q0.z * INV_DX;
        float bzf = floorf(gz - 0.5f);
        float fz = gz - bzf;
        int oz0 = nz0 - (int)bzf;

        float wxy = wq(ox, fx) * wq(oy, fy);
        float dpx = ((float)ox - fx) * DX;
        float dpy = ((float)oy - fy) * DX;
        float wz0 = 0.5f * (1.5f - fz) * (1.5f - fz);
        float wz1 = 0.75f - (fz - 1.0f) * (fz - 1.0f);
        float wz2 = 0.5f * (fz - 0.5f) * (fz - 0.5f);

        // dpz-independent partial sums; dpz coeffs: a2=A1.y, a5=A2.x, a8=A2.w
        float sx = A0.x + A0.w * dpx + A1.x * dpy;
        float sy = A0.y + A1.z * dpx + A1.w * dpy;
        float sz = A0.z + A2.y * dpx + A2.z * dpy;
        float wm = wxy * P_MASS;

#pragma unroll
        for (int k = 0; k < ZQ; ++k) {
          int oz = oz0 + k;
          if (oz < 0 || oz > 2) continue;
          float wzz = (oz == 0) ? wz0 : ((oz == 1) ? wz1 : wz2);
          float w = wxy * wzz;
          float dpz = ((float)oz - fz) * DX;
          accx[k] += w * (sx + A1.y * dpz);
          accy[k] += w * (sy + A2.x * dpz);
          accz[k] += w * (sz + A2.w * dpz);
          accm[k] += wzz * wm;
        }
      }
    }
  }

  if (!gotmask) return;

  float4* g4 = (float4*)grid;
#pragma unroll
  for (int k = 0; k < ZQ; ++k) {
    int nz = nz0 + k;
    if (!((gotmask >> k) & 1) || nz > N_GRID - 1) continue;
    float m = accm[k];
    float ovx = 0.0f, ovy = 0.0f, ovz = 0.0f;
    if (m > 0.0f) {
      float inv = 1.0f / fmaxf(m, 1e-10f);
      ovx = accx[k] * inv;
      ovy = accy[k] * inv;
      ovz = accz[k] * inv;
      ovy -= DT * GRAVITY;
    }
    if (nx < BOUND && ovx < 0.0f) ovx = 0.0f;
    if (nx >= N_GRID - BOUND && ovx > 0.0f) ovx = 0.0f;
    if (ny < BOUND && ovy < 0.0f) ovy = 0.0f;
    if (ny >= N_GRID - BOUND && ovy > 0.0f) ovy = 0.0f;
    if (nz < BOUND && ovz < 0.0f) ovz = 0.0f;
    if (nz >= N_GRID - BOUND && ovz > 0.0f) ovz = 0.0f;
    g4[(nx << 14) | (ny << 7) | nz] = make_float4(ovx, ovy, ovz, m);
  }
}

// ---------------- G2P: sorted order; no F access (deferred to dense epilogue) ----------------
__global__ __launch_bounds__(256) void mpm_g2p(
    const float4* __restrict__ posO, const float* __restrict__ grid,
    float* __restrict__ out_x, float* __restrict__ out_v,
    float* __restrict__ out_C) {
  int i = blockIdx.x * blockDim.x + threadIdx.x;
  if (i >= N_PART) return;

  float4 q0 = posO[i];
  int n = __float_as_int(q0.w);  // original particle index

  float px = q0.x, py = q0.y, pz = q0.z;
  float gx = px * INV_DX, gy = py * INV_DX, gz = pz * INV_DX;
  int bx = (int)floorf(gx - 0.5f);
  int by = (int)floorf(gy - 0.5f);
  int bz = (int)floorf(gz - 0.5f);
  float fx = gx - (float)bx, fy = gy - (float)by, fz = gz - (float)bz;

  float wx[3], wy[3], wz[3];
  wx[0] = 0.5f * (1.5f - fx) * (1.5f - fx);
  wx[1] = 0.75f - (fx - 1.0f) * (fx - 1.0f);
  wx[2] = 0.5f * (fx - 0.5f) * (fx - 0.5f);
  wy[0] = 0.5f * (1.5f - fy) * (1.5f - fy);
  wy[1] = 0.75f - (fy - 1.0f) * (fy - 1.0f);
  wy[2] = 0.5f * (fy - 0.5f) * (fy - 0.5f);
  wz[0] = 0.5f * (1.5f - fz) * (1.5f - fz);
  wz[1] = 0.75f - (fz - 1.0f) * (fz - 1.0f);
  wz[2] = 0.5f * (fz - 0.5f) * (fz - 0.5f);

  float vnx = 0.0f, vny = 0.0f, vnz = 0.0f;
  float Cn[9];
#pragma unroll
  for (int k = 0; k < 9; ++k) Cn[k] = 0.0f;

  const float4* g4 = (const float4*)grid;
  bool interior = (bx >= 0) & (by >= 0) & (bz >= 0) &
                  (bx + 2 < N_GRID) & (by + 2 < N_GRID) & (bz + 2 < N_GRID);

  if (interior) {
    int flat0 = (bx << 14) | (by << 7) | bz;
#pragma unroll
    for (int a = 0; a < 3; ++a) {
#pragma unroll
      for (int bb = 0; bb < 3; ++bb) {
#pragma unroll
        for (int c = 0; c < 3; ++c) {
          float weight = wx[a] * wy[bb] * wz[c];
          float dpx = ((float)a - fx) * DX;
          float dpy = ((float)bb - fy) * DX;
          float dpz = ((float)c - fz) * DX;
          float4 g = g4[flat0 + (a << 14) + (bb << 7) + c];
          vnx += weight * g.x;
          vny += weight * g.y;
          vnz += weight * g.z;
          Cn[0] += weight * g.x * dpx;
          Cn[1] += weight * g.x * dpy;
          Cn[2] += weight * g.x * dpz;
          Cn[3] += weight * g.y * dpx;
          Cn[4] += weight * g.y * dpy;
          Cn[5] += weight * g.y * dpz;
          Cn[6] += weight * g.z * dpx;
          Cn[7] += weight * g.z * dpy;
          Cn[8] += weight * g.z * dpz;
        }
      }
    }
  } else {
#pragma unroll
    for (int a = 0; a < 3; ++a) {
#pragma unroll
      for (int bb = 0; bb < 3; ++bb) {
#pragma unroll
        for (int c = 0; c < 3; ++c) {
          float weight = wx[a] * wy[bb] * wz[c];
          float dpx = ((float)a - fx) * DX;
          float dpy = ((float)bb - fy) * DX;
          float dpz = ((float)c - fz) * DX;
          int nxg = min(max(bx + a, 0), N_GRID - 1);
          int nyg = min(max(by + bb, 0), N_GRID - 1);
          int nzg = min(max(bz + c, 0), N_GRID - 1);
          float4 g = g4[(nxg << 14) | (nyg << 7) | nzg];
          vnx += weight * g.x;
          vny += weight * g.y;
          vnz += weight * g.z;
          Cn[0] += weight * g.x * dpx;
          Cn[1] += weight * g.x * dpy;
          Cn[2] += weight * g.x * dpz;
          Cn[3] += weight * g.y * dpx;
          Cn[4] += weight * g.y * dpy;
          Cn[5] += weight * g.y * dpz;
          Cn[6] += weight * g.z * dpx;
          Cn[7] += weight * g.z * dpy;
          Cn[8] += weight * g.z * dpz;
        }
      }
    }
  }

#pragma unroll
  for (int k = 0; k < 9; ++k) Cn[k] *= C_SCALE;

  out_x[n * 3 + 0] = px + DT * vnx;
  out_x[n * 3 + 1] = py + DT * vny;
  out_x[n * 3 + 2] = pz + DT * vnz;
  out_v[n * 3 + 0] = vnx;
  out_v[n * 3 + 1] = vny;
  out_v[n * 3 + 2] = vnz;
#pragma unroll
  for (int k = 0; k < 9; ++k) out_C[n * 9 + k] = Cn[k];
}

// ---------------- F epilogue: fully DENSE in n — F never crosses the sort ----------------
__global__ __launch_bounds__(256) void k_ffinal(
    const float* __restrict__ out_C, const float* __restrict__ F,
    float* __restrict__ out_F) {
  int n = blockIdx.x * blockDim.x + threadIdx.x;
  if (n >= N_PART) return;

  float A[9];
#pragma unroll
  for (int k = 0; k < 9; ++k) A[k] = DT * out_C[(size_t)n * 9 + k];
  A[0] += 1.0f; A[4] += 1.0f; A[8] += 1.0f;

  float Fl[9];
#pragma unroll
  for (int k = 0; k < 9; ++k) Fl[k] = F[(size_t)n * 9 + k];

#pragma unroll
  for (int r = 0; r < 3; ++r) {
#pragma unroll
    for (int k = 0; k < 3; ++k) {
      float s = A[r * 3 + 0] * Fl[0 * 3 + k] +
                A[r * 3 + 1] * Fl[1 * 3 + k] +
                A[r * 3 + 2] * Fl[2 * 3 + k];
      out_F[(size_t)n * 9 + r * 3 + k] = s;
    }
  }
}

extern "C" void kernel_launch(void* const* d_in, const int* in_sizes, int n_in,
                              void* d_out, int out_size, void* d_ws, size_t ws_size,
                              hipStream_t stream) {
  const float* x      = (const float*)d_in[0];
  const float* v      = (const float*)d_in[1];
  const float* C      = (const float*)d_in[2];
  const float* F      = (const float*)d_in[3];
  const float* stress = (const float*)d_in[4];

  float* out = (float*)d_out;
  char*  ws  = (char*)d_ws;

  const size_t GRID_BYTES  = (size_t)N_GRID3 * 4 * sizeof(float);   // 33.5 MB
  const size_t POSO_BYTES  = (size_t)N_PART * sizeof(float4);       // 8 MB
  const size_t AUX_BYTES   = (size_t)N_PART * 3 * sizeof(float4);   // 24 MB
  const size_t CNT_BYTES   = (size_t)N_GRID3 * sizeof(int);         // 8 MB
  const size_t START_BYTES = ((size_t)N_GRID3 + 1) * sizeof(int);   // 8 MB

  int pblocks = (N_PART + 255) / 256;  // 1954

  size_t off = 0;
  float*  grid   = (float*)(ws + off);  off += GRID_BYTES;
  float4* posO   = (float4*)(ws + off); off += POSO_BYTES;
  float4* aux    = (float4*)(ws + off); off += AUX_BYTES;
  int*    cnt    = (int*)(ws + off);    off += CNT_BYTES;
  int*    startp = (int*)(ws + off);    off += START_BYTES;
  int*    blkSum = (int*)(ws + off);    off += 2048 * sizeof(int);
  int*    blkOff = (int*)(ws + off);    off += 2048 * sizeof(int);
  int*    blkMin = (int*)(ws + off);    off += (size_t)pblocks * 3 * sizeof(int);
  int*    blkMax = (int*)(ws + off);    off += (size_t)pblocks * 3 * sizeof(int);
  int*    bbox   = (int*)(ws + off);    off += 16 * sizeof(int);

  hipMemsetAsync(cnt, 0, CNT_BYTES, stream);

  k_count<<<pblocks, 256, 0, stream>>>(x, cnt, blkMin, blkMax);
  k_scan1<<<2048, 256, 0, stream>>>(cnt, blkSum);
  k_scan2<<<1, 256, 0, stream>>>(blkSum, blkOff, startp, blkMin, blkMax, pblocks, bbox);
  k_scan3<<<2048, 256, 0, stream>>>(cnt, blkOff, startp);
  k_reorder<<<pblocks, 256, 0, stream>>>(x, v, C, stress, cnt, posO, aux);

  mpm_p2g<<<(N_GRID3 / ZQ + 255) / 256, 256, 0, stream>>>(startp, posO, aux, bbox, grid);

  float* out_x = out;
  float* out_v = out + (size_t)N_PART * 3;
  float* out_C = out + (size_t)N_PART * 6;
  float* out_F = out + (size_t)N_PART * 6 + (size_t)N_PART * 9;
  mpm_g2p<<<pblocks, 256, 0, stream>>>(posO, grid, out_x, out_v, out_C);
  k_ffinal<<<pblocks, 256, 0, stream>>>(out_C, F, out_F);
}